// Round 10
// baseline (271.145 us; speedup 1.0000x reference)
//
#include <hip/hip_runtime.h>
#include <hip/hip_bf16.h>
#include <math.h>

#define HH 512
#define WW 512
#define BB 8
#define TT 5
#define MID 16
#define HWSZ (HH*WW)      /* 262144 = 2^18 */
#define NPIX (BB*HWSZ)    /* 2097152 */

typedef __attribute__((ext_vector_type(8))) short bf16x8;
typedef __attribute__((ext_vector_type(4))) float f32x4;

// ---------- bf16 helpers ----------
__device__ inline unsigned short f2bf(float f){          // RNE (used in prep only)
  unsigned u = __float_as_uint(f);
  u = u + 0x7fffu + ((u >> 16) & 1u);
  return (unsigned short)(u >> 16);
}
// fast round-half-up pack of two floats -> bf16 pair (low16 = a, high16 = b)
__device__ inline unsigned packpair(float a, float b){
  unsigned ua = __float_as_uint(a) + 0x8000u;
  unsigned ub = __float_as_uint(b) + 0x8000u;
  return __builtin_amdgcn_perm(ub, ua, 0x07060302u);
}
__device__ inline float blo(unsigned u){ return __uint_as_float(u << 16); }
__device__ inline float bhi(unsigned u){ return __uint_as_float(u & 0xffff0000u); }

union U4B { uint4 u; bf16x8 h; };

// ---------- consts layout (floats, in cst) ----------
// [0] mean  [1] inv_std
// [2..145]   w1eff[16][9]
// [146..161] sc1   [162..177] bi1
// [242] bias
// [288..303] sc2a  [304..319] bi2a
// [320..335] sc3a  [336..351] bi3a

// ================= kernel 1: accumulate |raw_diff| + per-block partial stats =================
__global__ __launch_bounds__(256) void k_acc(const float* __restrict__ rd,
                                             float4* __restrict__ acc,
                                             float2* __restrict__ partial){
  int t = blockIdx.x * 256 + threadIdx.x;   // 0..524287
  int i = t << 2;
  int b = i >> 18, p = i & (HWSZ - 1);
  const float* base = rd + (size_t)b * 4 * HWSZ + p;
  float4 f0 = *(const float4*)(base);
  float4 f1 = *(const float4*)(base + HWSZ);
  float4 f2 = *(const float4*)(base + 2*HWSZ);
  float4 f3 = *(const float4*)(base + 3*HWSZ);
  float4 s4;
  s4.x = fabsf(f0.x) + fabsf(f1.x) + fabsf(f2.x) + fabsf(f3.x);
  s4.y = fabsf(f0.y) + fabsf(f1.y) + fabsf(f2.y) + fabsf(f3.y);
  s4.z = fabsf(f0.z) + fabsf(f1.z) + fabsf(f2.z) + fabsf(f3.z);
  s4.w = fabsf(f0.w) + fabsf(f1.w) + fabsf(f2.w) + fabsf(f3.w);
  acc[t] = s4;
  float s  = s4.x + s4.y + s4.z + s4.w;
  float s2 = s4.x*s4.x + s4.y*s4.y + s4.z*s4.z + s4.w*s4.w;
  #pragma unroll
  for (int off = 32; off; off >>= 1){
    s  += __shfl_down(s,  off);
    s2 += __shfl_down(s2, off);
  }
  __shared__ float ls[4], ls2[4];
  int lane = threadIdx.x & 63, wid = threadIdx.x >> 6;
  if (lane == 0){ ls[wid] = s; ls2[wid] = s2; }
  __syncthreads();
  if (threadIdx.x == 0)
    partial[blockIdx.x] = make_float2(ls[0]+ls[1]+ls[2]+ls[3],
                                      ls2[0]+ls2[1]+ls2[2]+ls2[3]);
}

// ================= kernel 2: reduce partials + folded weights / MFMA frags =================
__global__ __launch_bounds__(256) void k_prep(const float2* __restrict__ partial,
    const float* __restrict__ w1, const float* __restrict__ w2, const float* __restrict__ w3,
    const float* __restrict__ g1, const float* __restrict__ b1, const float* __restrict__ rm1, const float* __restrict__ rv1,
    const float* __restrict__ g2, const float* __restrict__ b2, const float* __restrict__ rm2, const float* __restrict__ rv2,
    const float* __restrict__ g3, const float* __restrict__ b3, const float* __restrict__ rm3, const float* __restrict__ rv3,
    const float* __restrict__ w4, const float* __restrict__ bias0,
    float* __restrict__ cst, unsigned* __restrict__ wsB2, unsigned* __restrict__ wsB3,
    uint4* __restrict__ wsB4){
  int t = threadIdx.x;
  double s = 0.0, s2 = 0.0;
  for (int j = t; j < 2048; j += 256){
    float2 v = partial[j];
    s += (double)v.x; s2 += (double)v.y;
  }
  #pragma unroll
  for (int off = 32; off; off >>= 1){
    s  += __shfl_down(s,  off);
    s2 += __shfl_down(s2, off);
  }
  __shared__ double ds[4], ds2[4];
  int lane = t & 63, wid = t >> 6;
  if (lane == 0){ ds[wid] = s; ds2[wid] = s2; }
  __syncthreads();
  if (t == 0){
    double S  = ds[0]+ds[1]+ds[2]+ds[3];
    double S2 = ds2[0]+ds2[1]+ds2[2]+ds2[3];
    double n = (double)NPIX;
    double mean = S / n;
    double var  = (S2 - n * mean * mean) / (n - 1.0);
    double sd   = sqrt(var);
    cst[0] = (float)mean;
    cst[1] = (float)(1.0 / (sd + 1e-6));
    cst[242] = bias0[0];
  }
  if (t < 144){
    int c = t / 9, k = t % 9;
    float sw = 0.f;
    for (int f = 0; f < TT; f++) sw += w1[c*45 + f*9 + k];
    cst[2 + t] = sw;
  }
  if (t < 16){
    float s1 = g1[t] * rsqrtf(rv1[t] + 1e-5f);
    cst[146 + t] = s1; cst[162 + t] = b1[t] - rm1[t] * s1;
    float c2 = g2[t] * rsqrtf(rv2[t] + 1e-5f);
    cst[288 + t] = c2; cst[304 + t] = b2[t] - rm2[t] * c2;
    float c3 = g3[t] * rsqrtf(rv3[t] + 1e-5f);
    cst[320 + t] = c3; cst[336 + t] = b3[t] - rm3[t] * c3;
  }
  // conv-weight fragments for 16x16x32 bf16 MFMA (A operand): lane holds
  // [out=lane&15][k=(lane>>4)*8+j], k -> tap = 2m + (k>>4), ci = k&15; tap 9 ZERO.
  for (int it = 0; it < 5; it++){
    int idx = it * 256 + t;          // 0..1279
    int m = idx >> 8, rem = idx & 255;
    int L = rem >> 2, jj = rem & 3;
    int out = L & 15, q = L >> 4;
    unsigned v2 = 0, v3 = 0;
    #pragma unroll
    for (int h = 0; h < 2; h++){
      int j = 2*jj + h;
      int k = q*8 + j;
      int tap = 2*m + (k >> 4);
      int ci = k & 15;
      unsigned bv2 = 0, bv3 = 0;
      if (tap < 9){
        bv2 = f2bf(w2[out*144 + ci*9 + tap]);
        bv3 = f2bf(w3[out*144 + ci*9 + tap]);
      }
      v2 |= bv2 << (16*h);
      v3 |= bv3 << (16*h);
    }
    wsB2[idx] = v2; wsB3[idx] = v3;
  }
  // B-fragments for w4 16x16x32 MFMA (K: ch 0..15 real, 16..31 ZERO), 3 N-chunks.
  if (t < 192){
    int c = t >> 6, L = t & 63;
    int n = L & 15, q = L >> 4;
    int o = c*16 + n;
    unsigned vv[4];
    #pragma unroll
    for (int jj = 0; jj < 4; jj++){
      unsigned pk = 0;
      #pragma unroll
      for (int h = 0; h < 2; h++){
        int j = 2*jj + h, kci = q*8 + j;
        unsigned bv = 0;
        if (kci < 16 && o < 45) bv = f2bf(w4[o*16 + kci]);
        pk |= bv << (16*h);
      }
      vv[jj] = pk;
    }
    wsB4[c*64 + L] = make_uint4(vv[0], vv[1], vv[2], vv[3]);
  }
}

// ======== kernel 3: FUSED conv1 (from LDS acc tile) + conv2 (MFMA from LDS) ========
#define TR 12
#define TC 68
__global__ __launch_bounds__(256) void k_conv12(const float* __restrict__ acc,
                                                const float* __restrict__ C,
                                                const unsigned* __restrict__ wsB2,
                                                uint2* __restrict__ h2){
  __shared__ float AT[14*72];             // 4032 B
  __shared__ uint4 PL[2][TR*TC];          // 26112 B
  int tid = threadIdx.x;
  int blk = blockIdx.x;                    // 8 xt | 64 yt | 8 b
  int xt = blk & 7, yt = (blk >> 3) & 63, b = blk >> 9;
  int y0 = yt << 3, x0 = xt << 6;
  float mean = C[0], inv = C[1];
  const float* ab = acc + ((size_t)b << 18);
  // ---- phase 0: stage normalized acc tile (coalesced), halo/pad = 0 ----
  #pragma unroll
  for (int it = 0; it < 4; it++){
    int idx = it*256 + tid;
    if (idx < 14*72){
      int r = (idx * 1821) >> 17;          // idx/72 exact for idx<1008
      int p = idx - r*72;
      int gy = y0 - 3 + r, gx = x0 - 3 + p;
      float v = 0.f;
      if ((unsigned)gy < HH && (unsigned)gx < WW)
        v = (ab[(gy << 9) + gx] - mean) * inv;
      AT[idx] = v;
    }
  }
  __syncthreads();
  // ---- phase 1: conv1 + BN + ReLU from LDS into PL; out-of-image h1 = 0 ----
  #pragma unroll
  for (int it = 0; it < 4; it++){
    int i = it*256 + tid;
    if (i < TR*TC){
      int r2 = (i * 241) >> 14;            // i/68 exact for i<816
      int p2 = i - r2*TC;
      int gy = y0 - 2 + r2, gx = x0 - 2 + p2;
      uint4 lo = make_uint4(0u,0u,0u,0u), hi = lo;
      if ((unsigned)gy < HH && (unsigned)gx < WW){
        float a[MID];
        #pragma unroll
        for (int o = 0; o < MID; o++) a[o] = 0.f;
        #pragma unroll
        for (int ky = 0; ky < 3; ky++){
          #pragma unroll
          for (int kx = 0; kx < 3; kx++){
            float m = AT[(r2 + ky)*72 + (p2 + kx)];
            int k = ky * 3 + kx;
            #pragma unroll
            for (int o = 0; o < MID; o++) a[o] = fmaf(C[2 + o*9 + k], m, a[o]);
          }
        }
        unsigned pk[8];
        #pragma unroll
        for (int j = 0; j < 8; j++){
          float v0 = fmaxf(0.f, fmaf(a[2*j],   C[146 + 2*j],   C[162 + 2*j]));
          float v1 = fmaxf(0.f, fmaf(a[2*j+1], C[146 + 2*j+1], C[162 + 2*j+1]));
          pk[j] = packpair(v0, v1);
        }
        lo = make_uint4(pk[0], pk[1], pk[2], pk[3]);
        hi = make_uint4(pk[4], pk[5], pk[6], pk[7]);
      }
      PL[0][r2*TC + p2] = lo;
      PL[1][r2*TC + p2] = hi;
    }
  }
  __syncthreads();
  // ---- phase 2: conv2 via MFMA, B-operand from LDS (tap-9 zeroed by weights) ----
  int lane = tid & 63, wv = tid >> 6;
  int col = lane & 15, q = lane >> 4;
  int chSel = q & 1;
  bool hiTap = (q >= 2);
  uint4 wfrag[5];
  #pragma unroll
  for (int m = 0; m < 5; m++) wfrag[m] = ((const uint4*)wsB2)[m*64 + lane];
  float4 sc = *(const float4*)&C[288 + q*4];
  float4 bi = *(const float4*)&C[304 + q*4];
  #pragma unroll
  for (int rr = 0; rr < 2; rr++){
    int ly = wv*2 + rr;
    #pragma unroll
    for (int g = 0; g < 4; g++){
      int lx = g << 4;
      f32x4 cc = {0.f, 0.f, 0.f, 0.f};
      #pragma unroll
      for (int m = 0; m < 5; m++){
        const int ta = 2*m, tb = (2*m + 1 > 8) ? 8 : (2*m + 1);  // tap9 -> tap8 addr (weight=0)
        int dy = (hiTap ? tb/3 : ta/3) - 1;
        int dx = (hiTap ? tb%3 : ta%3) - 1;
        int trow = ly + 2 + 2*dy;            // in [0,11]
        int tpx  = lx + 2 + col + 2*dx;      // in [0,67]
        U4B bv; bv.u = PL[chSel][trow*TC + tpx];
        U4B wb; wb.u = wfrag[m];
        cc = __builtin_amdgcn_mfma_f32_16x16x32_bf16(wb.h, bv.h, cc, 0, 0, 0);
      }
      float v0 = fmaxf(0.f, fmaf(cc[0], sc.x, bi.x));
      float v1 = fmaxf(0.f, fmaf(cc[1], sc.y, bi.y));
      float v2 = fmaxf(0.f, fmaf(cc[2], sc.z, bi.z));
      float v3 = fmaxf(0.f, fmaf(cc[3], sc.w, bi.w));
      int gy = y0 + ly, gx = x0 + lx + col;
      h2[(size_t)((b << 18) | (gy << 9) | gx)*4 + q] =
          make_uint2(packpair(v0, v1), packpair(v2, v3));
    }
  }
}

// ---------- conv3 MFMA core: A = weights, B = pixel patches (global) ----------
template<bool EDGE>
__device__ inline f32x4 convW4(const uint4* __restrict__ hin, const uint4 wfrag[5],
                               int b, int y, int x0, int col, int q, f32x4 cc){
  int chSel = q & 1;
  bool hiTap = (q >= 2);
  #pragma unroll
  for (int m = 0; m < 5; m++){
    const int ta = 2*m, tb = (2*m + 1 > 8) ? 8 : (2*m + 1);
    int dy = (hiTap ? tb/3 : ta/3) - 1;
    int dx = (hiTap ? tb%3 : ta%3) - 1;
    int yy = y + dy * 4;
    int xx = x0 + col + dx * 4;
    U4B a;
    if (EDGE){
      bool valid = ((unsigned)yy < HH) && ((unsigned)xx < WW);
      a.u = make_uint4(0u, 0u, 0u, 0u);
      if (valid) a.u = hin[(((unsigned)((b << 18) | (yy << 9) | xx)) << 1) | (unsigned)chSel];
    } else {
      a.u = hin[(((unsigned)((b << 18) | (yy << 9) | xx)) << 1) | (unsigned)chSel];
    }
    U4B bb; bb.u = wfrag[m];
    cc = __builtin_amdgcn_mfma_f32_16x16x32_bf16(bb.h, a.h, cc, 0, 0, 0);
  }
  return cc;
}

// ======== kernel 4: conv3 + w4 + sigmoid + enhance — TLP-restructured ========
// Block = 64 px. Wave wv computes group g=wv (stage 1+2) -> kern in block LDS
// (rows 52 shorts: write banks 8q^col/2 all-distinct). __syncthreads. Stage 3
// splits by frame: wave wv does t=wv (wave 0 also t=4). 6.7 KB LDS -> 8 blocks/CU.
__global__ __launch_bounds__(256) void k_conv3m(const uint4* __restrict__ h2,
                                                const float* __restrict__ C,
                                                const unsigned* __restrict__ wsB3,
                                                const uint4* __restrict__ wsB4,
                                                const float* __restrict__ xal,
                                                float* __restrict__ out){
  __shared__ unsigned LkU[64*26];            // 6656 B / block
  unsigned short* Lk = (unsigned short*)LkU; // row stride 52 shorts
  int tid = threadIdx.x;
  int lane = tid & 63, wv = tid >> 6;
  int base = blockIdx.x << 6;                // 64 px per block
  int b = base >> 18, rem = base & (HWSZ - 1);
  int y = rem >> 9, wx = rem & 511;
  int col = lane & 15, q = lane >> 4;
  uint4 wfrag[5];
  #pragma unroll
  for (int m = 0; m < 5; m++) wfrag[m] = ((const uint4*)wsB3)[m*64 + lane];
  uint4 bw[3];
  #pragma unroll
  for (int c = 0; c < 3; c++) bw[c] = wsB4[c*64 + lane];
  float4 sc = *(const float4*)&C[320 + q*4];
  float4 bi = *(const float4*)&C[336 + q*4];
  float cb = C[242];                                    // bias
  int src0 = col + q*32;
  int src1 = src0 + 16;

  // ---- stage 1: conv3 MFMA for group g = wv ----
  int x0 = wx + (wv << 4);
  bool fast = (y >= 4) && (y < 508) && (x0 >= 4) && (x0 <= 492);
  f32x4 cc = {0.f, 0.f, 0.f, 0.f};
  if (fast) cc = convW4<false>(h2, wfrag, b, y, x0, col, q, cc);
  else      cc = convW4<true >(h2, wfrag, b, y, x0, col, q, cc);
  float v0 = fmaxf(0.f, fmaf(cc[0], sc.x, bi.x));
  float v1 = fmaxf(0.f, fmaf(cc[1], sc.y, bi.y));
  float v2 = fmaxf(0.f, fmaf(cc[2], sc.z, bi.z));
  float v3 = fmaxf(0.f, fmaf(cc[3], sc.w, bi.w));
  int pk01 = (int)packpair(v0, v1);
  int pk23 = (int)packpair(v2, v3);

  // ---- C-layout -> A-layout via shuffles (q>=2 garbage zeroed by wsB4 K-pad) ----
  U4B a;
  a.u.x = (unsigned)__shfl(pk01, src0);
  a.u.y = (unsigned)__shfl(pk23, src0);
  a.u.z = (unsigned)__shfl(pk01, src1);
  a.u.w = (unsigned)__shfl(pk23, src1);

  // ---- stage 2: w4 MFMA (K=16 padded to 32) + sigmoid -> kern LDS ----
  #pragma unroll
  for (int c = 0; c < 3; c++){
    f32x4 aw = {cb, cb, cb, cb};
    U4B bb; bb.u = bw[c];
    aw = __builtin_amdgcn_mfma_f32_16x16x32_bf16(a.h, bb.h, aw, 0, 0, 0);
    #pragma unroll
    for (int r = 0; r < 4; r++){
      float e  = __expf(-aw[r]);
      float rc = __builtin_amdgcn_rcpf(1.f + e);
      float kern = fmaf(10.f, rc, 0.1f);
      unsigned u = __float_as_uint(kern) + 0x8000u;
      Lk[((wv << 4) + q*4 + r)*52 + c*16 + col] = (unsigned short)(u >> 16);
    }
  }
  __syncthreads();

  // ---- stage 3: (px, t) work item; lane -> px = wx+lane, wave -> t ----
  int px = wx + lane;
  bool mxl = (px > 0), mxr = (px < 511), mym = (y > 0), myp = (y < 511);
  bool msk[9] = { mym&&mxl, mym, mym&&mxr,
                  mxl,      true, mxr,
                  myp&&mxl, myp, myp&&mxr };
  int rowm = mym ? -2048 : 0;
  int rowp = myp ?  2048 : 0;
  int loff = mxl ? -4 : 0;
  int roff = mxr ?  4 : 0;
  const char* base0 = (const char*)(xal + ((size_t)(b*TT) << 18) + (y << 9) + px);
  #pragma unroll
  for (int rep = 0; rep < 2; rep++){
    int t = (rep == 0) ? wv : 4;
    if (rep == 1 && wv != 0) break;
    // kern shorts [t*9, t*9+9) of row `lane`: 6 dword reads from aligned base
    int d0 = (t*9) >> 1, off = (t*9) & 1;
    unsigned kv[6];
    #pragma unroll
    for (int j = 0; j < 6; j++) kv[j] = LkU[lane*26 + d0 + j];
    const char* pc = base0 + (size_t)t * (HWSZ*4);
    const char* pm = pc + rowm;
    const char* pp = pc + rowp;
    float xv[9];
    xv[0] = *(const float*)(pm + loff);
    xv[1] = *(const float*)(pm);
    xv[2] = *(const float*)(pm + roff);
    xv[3] = *(const float*)(pc + loff);
    xv[4] = *(const float*)(pc);
    xv[5] = *(const float*)(pc + roff);
    xv[6] = *(const float*)(pp + loff);
    xv[7] = *(const float*)(pp);
    xv[8] = *(const float*)(pp + roff);
    float ov = 0.f;
    #pragma unroll
    for (int k = 0; k < 9; k++){
      int nrel = off + k;
      unsigned u = kv[nrel >> 1];
      float kf = (nrel & 1) ? bhi(u) : blo(u);
      float kern = msk[k] ? kf : 0.f;
      ov = fmaf(kern, xv[k], ov);
    }
    out[((size_t)(b*TT + t) << 18) + (y << 9) + px] = ov;
  }
}

extern "C" void kernel_launch(void* const* d_in, const int* in_sizes, int n_in,
                              void* d_out, int out_size, void* d_ws, size_t ws_size,
                              hipStream_t stream){
  const float* xal = (const float*)d_in[0];
  const float* rd  = (const float*)d_in[1];
  const float* w1  = (const float*)d_in[2];
  const float* g1  = (const float*)d_in[3];
  const float* b1  = (const float*)d_in[4];
  const float* rm1 = (const float*)d_in[5];
  const float* rv1 = (const float*)d_in[6];
  const float* w2  = (const float*)d_in[7];
  const float* g2  = (const float*)d_in[8];
  const float* b2  = (const float*)d_in[9];
  const float* rm2 = (const float*)d_in[10];
  const float* rv2 = (const float*)d_in[11];
  const float* w3  = (const float*)d_in[12];
  const float* g3  = (const float*)d_in[13];
  const float* b3  = (const float*)d_in[14];
  const float* rm3 = (const float*)d_in[15];
  const float* rv3 = (const float*)d_in[16];
  const float* w4  = (const float*)d_in[17];
  const float* bias= (const float*)d_in[18];
  float* out = (float*)d_out;

  char* ws = (char*)d_ws;
  float2*   partial = (float2*)ws;                    // 16 KB
  float*    cst   = (float*)(ws + 16384);             // 352 floats used
  unsigned* wsB2  = (unsigned*)(ws + 32768);          // 5 KB
  unsigned* wsB3  = (unsigned*)(ws + 40960);          // 5 KB
  uint4*    wsB4  = (uint4*)(ws + 49152);             // 3 KB
  float*    acc   = (float*)(ws + 65536);             // 8 MB
  char*     h2    = (char*)(ws + 65536 + (size_t)NPIX*4);                     // 64 MB

  k_acc<<<2048, 256, 0, stream>>>(rd, (float4*)acc, partial);
  k_prep<<<1, 256, 0, stream>>>(partial, w1, w2, w3,
                                g1, b1, rm1, rv1,
                                g2, b2, rm2, rv2,
                                g3, b3, rm3, rv3, w4, bias, cst, wsB2, wsB3, wsB4);
  k_conv12<<<4096, 256, 0, stream>>>(acc, cst, wsB2, (uint2*)h2);
  k_conv3m<<<NPIX/64, 256, 0, stream>>>((const uint4*)h2, cst, wsB3, wsB4, xal, out);
}